// Round 1
// baseline (189.118 us; speedup 1.0000x reference)
//
#include <hip/hip_runtime.h>

// Dynamic lightweight convolution, fp32 fused kernel.
// B=8, S=2048, D=1024, K=7, H=16, L=2042.
// Phase 1: logits[r][o] = x[b, l0+6+r, :] . W[:, o] + bias[o], o = k*16+h
// Phase 2: softmax over k (in registers: thread t owns head h=t&15, all 7 k)
// Phase 3: out[b,l,d] = (1/7) sum_k P[l][k][d%16] * x[b,l+k,d]

#define KK   7
#define HH   16
#define DD   1024
#define SS   2048
#define LL   2042
#define NO   112        // K*H
#define TL   32         // output rows per block
#define KT   64         // K-dim tile of the GEMM
#define NKT  16         // 1024/64

// LDS layout (floats):
//   [0, 7168)      Wt2: transposed W tile [o=112][j=64], XOR-swizzled
//   [7168, 9216)   xt : x tile [r=32][j=64], XOR-swizzled
//   [0, 3584)      P  : softmax probs [r=32][k=7][h=16]  (reuses Wt2 region)
__global__ __launch_bounds__(256, 2)
void dlconv(const float* __restrict__ x, const float* __restrict__ W,
            const float* __restrict__ bias, float* __restrict__ out)
{
    __shared__ float lds[9216];
    const int t  = threadIdx.x;
    const int lb = blockIdx.x;
    const int b  = blockIdx.y;
    const int l0 = lb * TL;
    const int og = t & 15;   // head h this thread owns
    const int rg = t >> 4;   // row group: rows rg*2, rg*2+1

    const float* xb = x + (size_t)b * SS * DD;

    float acc[2][KK];
#pragma unroll
    for (int q = 0; q < 2; ++q)
#pragma unroll
        for (int i = 0; i < KK; ++i) acc[q][i] = 0.f;

    for (int kt = 0; kt < NKT; ++kt) {
        // ---- stage x tile: rows l0+6 .. l0+37, cols kt*64..+63 ----
#pragma unroll
        for (int s = 0; s < 2; ++s) {
            int f4  = t + 256 * s;          // 0..511
            int row = f4 >> 4;              // 0..31
            int col = (f4 & 15) << 2;       // 0..60
            int gr  = l0 + 6 + row; gr = gr < SS ? gr : SS - 1;  // clamp (rows unused if OOB)
            float4 v = *(const float4*)(xb + (size_t)gr * DD + kt * KT + col);
            *(float4*)(lds + 7168 + ((row * 64 + col) ^ ((row & 7) << 2))) = v;
        }
        // ---- stage W tile transposed: Wt2[o][j] = W[kt*64+j][o] ----
#pragma unroll
        for (int s = 0; s < 7; ++s) {
            int idx = t + 256 * s;          // 0..1791
            int j   = idx / 28;
            int oc  = (idx - j * 28) << 2;  // 0,4,...,108
            const float4 w4 = *(const float4*)(W + (size_t)(kt * KT + j) * NO + oc);
            lds[((oc + 0) * 64 + j) ^ (((oc + 0) & 7) << 2)] = w4.x;
            lds[((oc + 1) * 64 + j) ^ (((oc + 1) & 7) << 2)] = w4.y;
            lds[((oc + 2) * 64 + j) ^ (((oc + 2) & 7) << 2)] = w4.z;
            lds[((oc + 3) * 64 + j) ^ (((oc + 3) & 7) << 2)] = w4.w;
        }
        __syncthreads();
        // ---- GEMM inner: acc[q][i] += xt[r][j..j+3] . Wt2[i*16+og][j..j+3] ----
#pragma unroll 4
        for (int j = 0; j < KT; j += 4) {
            const int r0 = rg * 2;
            float4 xv0 = *(const float4*)(lds + 7168 + (((r0 + 0) * 64 + j) ^ (((r0 + 0) & 7) << 2)));
            float4 xv1 = *(const float4*)(lds + 7168 + (((r0 + 1) * 64 + j) ^ (((r0 + 1) & 7) << 2)));
#pragma unroll
            for (int i = 0; i < KK; ++i) {
                int o = i * 16 + og;
                float4 wv = *(const float4*)(lds + ((o * 64 + j) ^ ((o & 7) << 2)));
                acc[0][i] += xv0.x * wv.x + xv0.y * wv.y + xv0.z * wv.z + xv0.w * wv.w;
                acc[1][i] += xv1.x * wv.x + xv1.y * wv.y + xv1.z * wv.z + xv1.w * wv.w;
            }
        }
        __syncthreads();
    }

    // ---- bias + softmax over k, entirely in registers; write P to LDS ----
#pragma unroll
    for (int q = 0; q < 2; ++q) {
        int r = rg * 2 + q;
        float v[KK];
        float m = -1e30f;
#pragma unroll
        for (int i = 0; i < KK; ++i) {
            v[i] = acc[q][i] + bias[i * 16 + og];
            m = fmaxf(m, v[i]);
        }
        float ssum = 0.f;
#pragma unroll
        for (int i = 0; i < KK; ++i) { v[i] = __expf(v[i] - m); ssum += v[i]; }
        float inv = 1.f / (7.f * ssum);   // fold the mean's 1/K into P
#pragma unroll
        for (int i = 0; i < KK; ++i) lds[(r * 7 + i) * 16 + og] = v[i] * inv;
    }
    __syncthreads();

    // ---- conv phase: out[b, l0+r, d] = sum_k P[r][k][d%16] * x[b, l0+r+k, d] ----
    const int d0 = t << 2;                  // 0..1020, this thread's 4 channels
    int nvr = LL - l0; nvr = nvr < TL ? nvr : TL;
    for (int r = 0; r < nvr; ++r) {
        float4 o4 = make_float4(0.f, 0.f, 0.f, 0.f);
#pragma unroll
        for (int k = 0; k < KK; ++k) {
            float4 xv = *(const float4*)(xb + (size_t)(l0 + r + k) * DD + d0);
            float4 pv = *(const float4*)(lds + (r * 7 + k) * 16 + (d0 & 15));
            o4.x += pv.x * xv.x;
            o4.y += pv.y * xv.y;
            o4.z += pv.z * xv.z;
            o4.w += pv.w * xv.w;
        }
        *(float4*)(out + ((size_t)b * LL + l0 + r) * DD + d0) = o4;
    }
}

extern "C" void kernel_launch(void* const* d_in, const int* in_sizes, int n_in,
                              void* d_out, int out_size, void* d_ws, size_t ws_size,
                              hipStream_t stream) {
    const float* x    = (const float*)d_in[0];
    const float* W    = (const float*)d_in[1];
    const float* bias = (const float*)d_in[2];
    float* out        = (float*)d_out;
    dim3 grid((LL + TL - 1) / TL, 8);   // 64 x 8 = 512 blocks
    dlconv<<<grid, 256, 0, stream>>>(x, W, bias, out);
}

// Round 2
// 73.392 us; speedup vs baseline: 2.5768x; 2.5768x over previous
//
#include <hip/hip_runtime.h>

// Dynamic lightweight convolution, MFMA-GEMM + fused softmax/conv.
// B=8, S=2048, D=1024, K=7, H=16, L=2042.
// Phase 1 (MFMA bf16): logits[r][o] = x[b, l0+6+r, :] . W[:, o], o = k*16+h
// Phase 2: +bias, softmax over k (thread owns head h, all 7 k in registers)
// Phase 3: out[b,l,d] = sum_k P[l][k][d%16] * x[b,l+k,d]   (1/7 folded into P)

#define KK   7
#define HH   16
#define DD   1024
#define SS   2048
#define LL   2042
#define NO   112
#define TL   32         // output rows per block
#define KT   128        // K-chunk of the GEMM
#define NKT  8          // 1024/128

typedef __attribute__((ext_vector_type(8))) short   bf16x8;
typedef __attribute__((ext_vector_type(4))) float   f32x4;

__device__ __forceinline__ unsigned short f2bf(float f) {
    unsigned int u = __builtin_bit_cast(unsigned int, f);
    u += 0x7fffu + ((u >> 16) & 1u);          // RNE (no NaN in this data)
    return (unsigned short)(u >> 16);
}
__device__ __forceinline__ unsigned int bfpack(float lo, float hi) {
    return (unsigned int)f2bf(lo) | ((unsigned int)f2bf(hi) << 16);
}

// LDS map (bytes), phase 1: A bf16 [32][128] swz @0..8192, Bt bf16 [128][128] swz @8192..40960
// phase 2/3 (after sync):  Lg f32 [32][113] @0..14464,  P f32 [32][7][16] @16384..30720
__global__ __launch_bounds__(256, 2)
void dlconv(const float* __restrict__ x, const float* __restrict__ W,
            const float* __restrict__ bias, float* __restrict__ out)
{
    __shared__ __align__(16) unsigned char smem[40960];
    float* lf = (float*)smem;
    const int t    = threadIdx.x;
    const int lb   = blockIdx.x, b = blockIdx.y;
    const int l0   = lb * TL;
    const int lane = t & 63, wid = t >> 6;
    const int mh   = wid & 1;        // M-half (rows mh*16 .. +15)
    const int ng   = wid >> 1;       // N-group (n-tiles ng*4 .. +3)
    const int frow = lane & 15;      // fragment row/col index
    const int fq   = lane >> 4;      // fragment k-quarter
    const float* xb = x + (size_t)b * SS * DD;

    f32x4 acc[4];
#pragma unroll
    for (int i = 0; i < 4; ++i) acc[i] = (f32x4)0.f;

    for (int kt = 0; kt < NKT; ++kt) {
        const int kb = kt * KT;
        // ---- stage A: x rows l0+6..l0+37, k = kb..kb+127, bf16, XOR-swizzled ----
#pragma unroll
        for (int s = 0; s < 4; ++s) {
            int idx = t + 256 * s;              // 0..1023 = 32 rows x 32 float4
            int row = idx >> 5, col = (idx & 31) << 2;
            int gr  = l0 + 6 + row; gr = gr < SS ? gr : SS - 1;
            float4 v = *(const float4*)(xb + (size_t)gr * DD + kb + col);
            unsigned int p0 = bfpack(v.x, v.y), p1 = bfpack(v.z, v.w);
            int addr = (row * 256 + col * 2) ^ ((row & 7) << 4);
            *(uint2*)(smem + addr) = make_uint2(p0, p1);
        }
        // ---- stage Bt[n][k] = W[kb+k][n], bf16, XOR-swizzled (k-pairs packed) ----
#pragma unroll
        for (int s = 0; s < 7; ++s) {
            int idx = t + 256 * s;              // 0..1791 = 64 k-pairs x 28 n4
            int k2  = idx / 28, n4 = (idx - k2 * 28) << 2;
            const float* wp = W + (size_t)(kb + 2 * k2) * NO + n4;
            float4 w0 = *(const float4*)wp;
            float4 w1 = *(const float4*)(wp + NO);
            int koff = k2 << 2;                 // byte offset 2*kloc, kloc=2*k2
#pragma unroll
            for (int j = 0; j < 4; ++j) {
                int n = n4 + j;
                float e0 = (j == 0) ? w0.x : (j == 1) ? w0.y : (j == 2) ? w0.z : w0.w;
                float e1 = (j == 0) ? w1.x : (j == 1) ? w1.y : (j == 2) ? w1.z : w1.w;
                int addr = 8192 + ((n * 256 + koff) ^ ((n & 7) << 4));
                *(unsigned int*)(smem + addr) = bfpack(e0, e1);
            }
        }
        __syncthreads();
        // ---- MFMA: 4 K-steps of 32, each wave 4 N-tiles ----
#pragma unroll
        for (int ksl = 0; ksl < 4; ++ksl) {
            int kloc = ksl * 32 + fq * 8;
            int arow = mh * 16 + frow;
            bf16x8 af = *(const bf16x8*)(smem + ((arow * 256 + kloc * 2) ^ ((arow & 7) << 4)));
#pragma unroll
            for (int i = 0; i < 4; ++i) {
                int n = (ng * 4 + i) * 16 + frow;
                bf16x8 bfr = *(const bf16x8*)(smem + 8192 + ((n * 256 + kloc * 2) ^ ((n & 7) << 4)));
                acc[i] = __builtin_amdgcn_mfma_f32_16x16x32_bf16(af, bfr, acc[i], 0, 0, 0);
            }
        }
        __syncthreads();   // also protects the Lg overwrite after the last chunk
    }

    // ---- write logits Lg[r][o], stride 113 to spread banks ----
#pragma unroll
    for (int i = 0; i < 4; ++i) {
        int nt = ng * 4 + i;
        if (nt < 7) {
#pragma unroll
            for (int reg = 0; reg < 4; ++reg) {
                int r = mh * 16 + fq * 4 + reg;
                lf[r * 113 + nt * 16 + frow] = acc[i][reg];
            }
        }
    }
    __syncthreads();

    // ---- bias + softmax over k (fp32, in registers), P -> LDS @ float 4096 ----
    const int og = t & 15, rg = t >> 4;
#pragma unroll
    for (int q = 0; q < 2; ++q) {
        int r = rg * 2 + q;
        float v[KK];
        float m = -1e30f;
#pragma unroll
        for (int i = 0; i < KK; ++i) {
            v[i] = lf[r * 113 + i * 16 + og] + bias[i * 16 + og];
            m = fmaxf(m, v[i]);
        }
        float ssum = 0.f;
#pragma unroll
        for (int i = 0; i < KK; ++i) { v[i] = __expf(v[i] - m); ssum += v[i]; }
        float inv = 1.f / (7.f * ssum);
#pragma unroll
        for (int i = 0; i < KK; ++i) lf[4096 + (r * 7 + i) * 16 + og] = v[i] * inv;
    }
    __syncthreads();

    // ---- conv: out[b, l0+r, d] = sum_k P[r][k][d%16] * x[b, l0+r+k, d] ----
    const int d0 = t << 2;
    int nvr = LL - l0; nvr = nvr < TL ? nvr : TL;
    for (int r = 0; r < nvr; ++r) {
        float4 o4 = make_float4(0.f, 0.f, 0.f, 0.f);
#pragma unroll
        for (int k = 0; k < KK; ++k) {
            float4 xv = *(const float4*)(xb + (size_t)(l0 + r + k) * DD + d0);
            float4 pv = *(const float4*)(lf + 4096 + (r * 7 + k) * 16 + (d0 & 15));
            o4.x += pv.x * xv.x;
            o4.y += pv.y * xv.y;
            o4.z += pv.z * xv.z;
            o4.w += pv.w * xv.w;
        }
        *(float4*)(out + ((size_t)b * LL + l0 + r) * DD + d0) = o4;
    }
}

extern "C" void kernel_launch(void* const* d_in, const int* in_sizes, int n_in,
                              void* d_out, int out_size, void* d_ws, size_t ws_size,
                              hipStream_t stream) {
    const float* x    = (const float*)d_in[0];
    const float* W    = (const float*)d_in[1];
    const float* bias = (const float*)d_in[2];
    float* out        = (float*)d_out;
    dim3 grid((LL + TL - 1) / TL, 8);   // 64 x 8 = 512 blocks
    dlconv<<<grid, 256, 0, stream>>>(x, W, bias, out);
}